// Round 5
// baseline (326.997 us; speedup 1.0000x reference)
//
#include <hip/hip_runtime.h>
#include <cstdint>
#include <cstddef>

#define BB 64
#define PP 8732
#define OO 32
#define CC 81
#define NBM 35    // k_match blocks per image (ceil(8732/256))
#define TR 64     // rows per k_ce block
#define NBC 137   // k_ce blocks per image (ceil(8732/64)); last block has 28 rows (28%4==0)

// ---------- kernel A: per-prior best object + per-block per-object best prior ----------
__global__ __launch_bounds__(256) void k_match(
    const float* __restrict__ gt_boxes,      // [B,O,4] coco pixel
    const float4* __restrict__ priors,       // [P] cxcy
    float* __restrict__ ovl, int* __restrict__ obj,
    unsigned long long* __restrict__ part)   // [B,NBM,O] packed (iou_bits<<32)|(~p)
{
    int b = blockIdx.y, blk = blockIdx.x;
    int tid = threadIdx.x;
    int p = blk * 256 + tid;
    bool pv = p < PP;
    __shared__ float bx1[OO], by1[OO], bx2[OO], by2[OO], bar[OO];
    __shared__ float mat[OO][264];           // stride 264 -> 2-way banks max (free)
    __shared__ unsigned long long po[OO][8];
    if (tid < OO) {
        const float* g = gt_boxes + ((size_t)b * OO + tid) * 4;
        float x1 = g[0] / 224.0f, y1 = g[1] / 224.0f;
        float x2 = (g[0] + g[2]) / 224.0f, y2 = (g[1] + g[3]) / 224.0f;
        bx1[tid] = x1; by1[tid] = y1; bx2[tid] = x2; by2[tid] = y2;
        bar[tid] = (x2 - x1) * (y2 - y1);
    }
    __syncthreads();
    float4 pr = priors[pv ? p : 0];
    float px1 = pr.x - pr.z * 0.5f, py1 = pr.y - pr.w * 0.5f;
    float px2 = pr.x + pr.z * 0.5f, py2 = pr.y + pr.w * 0.5f;
    float parea = (px2 - px1) * (py2 - py1);
    float best = -1.0f; int bo = 0;
    #pragma unroll
    for (int o = 0; o < OO; ++o) {
        float lx = fmaxf(bx1[o], px1), ly = fmaxf(by1[o], py1);
        float rx = fminf(bx2[o], px2), ry = fminf(by2[o], py2);
        float w = fmaxf(rx - lx, 0.0f), h = fmaxf(ry - ly, 0.0f);
        float inter = w * h;
        float iou = inter / (bar[o] + parea - inter);
        iou = pv ? iou : 0.0f;               // invalid priors can't win
        mat[o][tid] = iou;
        if (iou > best) { best = iou; bo = o; }   // strict > : first max (numpy argmax)
    }
    if (pv) {
        size_t idx = (size_t)b * PP + p;
        ovl[idx] = best;
        obj[idx] = bo;
    }
    __syncthreads();
    // per-object partial argmax over this block's 256 priors
    {
        int o = tid >> 3, j = tid & 7;
        float bv = -1.0f; int bt = 0;
        #pragma unroll
        for (int k = 0; k < 32; ++k) {
            int t = j + 8 * k;
            float v = mat[o][t];
            if (v > bv) { bv = v; bt = t; }
        }
        unsigned pg = (unsigned)(blk * 256 + bt);
        po[o][j] = ((unsigned long long)__float_as_uint(bv) << 32)
                 | (unsigned long long)(0xFFFFFFFFu - pg);
    }
    __syncthreads();
    if (tid < OO) {
        unsigned long long m = po[tid][0];
        #pragma unroll
        for (int j = 1; j < 8; ++j) if (po[tid][j] > m) m = po[tid][j];
        part[((size_t)b * NBM + blk) * OO + tid] = m;
    }
}

// ---------- kernel A2: fold partials + forced assignment (ascending o = numpy last-wins) ----------
__global__ void k_force(const unsigned long long* __restrict__ part,
                        float* __restrict__ ovl, int* __restrict__ obj)
{
    int b = blockIdx.x;
    __shared__ int s_pfo[OO];
    int t = threadIdx.x;
    if (t < OO) {
        unsigned long long m = part[((size_t)b * NBM + 0) * OO + t];
        for (int blk = 1; blk < NBM; ++blk) {
            unsigned long long v = part[((size_t)b * NBM + blk) * OO + t];
            if (v > m) m = v;                // packed max: larger iou, then smaller p
        }
        s_pfo[t] = (int)(0xFFFFFFFFu - (unsigned)(m & 0xFFFFFFFFull));
    }
    __syncthreads();
    if (t == 0) {
        for (int o = 0; o < OO; ++o) {
            int p = s_pfo[o];
            obj[(size_t)b * PP + p] = o;
            ovl[(size_t)b * PP + p] = 1.0f;
        }
    }
}

// ---------- kernel B: fused CE + loc loss with LDS-staged coalesced score tile ----------
__global__ __launch_bounds__(256) void k_ce(
    const float* __restrict__ scores,        // [B,P,C]
    const float4* __restrict__ pred_locs,
    const float* __restrict__ gt_boxes,
    const int* __restrict__ gt_labels,
    const float4* __restrict__ priors,
    const float* __restrict__ ovl, const int* __restrict__ obj,
    float* __restrict__ ceneg,
    float* __restrict__ pp_posce, float* __restrict__ pp_sl1,
    int* __restrict__ pp_np)
{
    int b = blockIdx.y;
    int p0 = blockIdx.x * TR;
    int nrows = PP - p0; if (nrows > TR) nrows = TR;   // 64 or 28, both %4==0
    int n4 = nrows * CC / 4;                           // exact
    __shared__ float4 sv4[TR * CC / 4];                // 1296 float4 = 20.7 KB
    __shared__ int s_lab[TR], s_ob[TR];
    __shared__ float s_posce, s_sl1;
    __shared__ int s_np;
    int tid = threadIdx.x;
    if (tid == 0) { s_posce = 0.f; s_sl1 = 0.f; s_np = 0; }
    // labels: one coalesced 64-wide read of ovl/obj
    if (tid < nrows) {
        size_t idx = (size_t)b * PP + p0 + tid;
        float ov = ovl[idx];
        int ob = obj[idx];
        s_ob[tid] = ob;
        s_lab[tid] = (ov < 0.5f) ? 0 : gt_labels[b * OO + ob];
    }
    // stage score tile; base is 16B-aligned ((b*8732+p0)*81 % 4 == 0)
    const float4* src = (const float4*)(scores + ((size_t)b * PP + p0) * CC);
    for (int i = tid; i < n4; i += 256) sv4[i] = src[i];
    __syncthreads();
    const float* sv = (const float*)sv4;
    int g = tid >> 4, l = tid & 15;
    #pragma unroll
    for (int rr = 0; rr < 4; ++rr) {
        int r = g * 4 + rr;                  // uniform within the 16-lane group
        if (r >= nrows) break;
        int lab = s_lab[r];
        const float* row = sv + r * CC;
        float se = 0.f, xl = 0.f;
        #pragma unroll
        for (int k = 0; k < 6; ++k) {
            int c = l + 16 * k;
            if (c < CC) {
                float x = row[c];
                se += __expf(x);
                if (c == lab) xl = x;
            }
        }
        #pragma unroll
        for (int s = 8; s >= 1; s >>= 1) {
            se += __shfl_xor(se, s, 16);
            xl += __shfl_xor(xl, s, 16);
        }
        if (l == 0) {
            int p = p0 + r;
            size_t idx = (size_t)b * PP + p;
            float ce = fmaxf(__logf(se) - xl, 0.0f);
            float cn = ce;
            if (lab != 0) {
                cn = 0.f;
                int ob = s_ob[r];
                float4 pl = pred_locs[idx];
                float4 pq = priors[p];
                const float* gg = gt_boxes + ((size_t)b * OO + ob) * 4;
                float x1 = gg[0] / 224.0f, y1 = gg[1] / 224.0f;
                float x2 = (gg[0] + gg[2]) / 224.0f, y2 = (gg[1] + gg[3]) / 224.0f;
                float cx = (x1 + x2) * 0.5f, cy = (y1 + y2) * 0.5f;
                float w = x2 - x1, h = y2 - y1;
                float tx = (cx - pq.x) / (pq.z / 10.0f);
                float ty = (cy - pq.y) / (pq.w / 10.0f);
                float tw = __logf(w / pq.z) * 5.0f;
                float th = __logf(h / pq.w) * 5.0f;
                float d0 = fabsf(pl.x - tx), d1 = fabsf(pl.y - ty);
                float d2 = fabsf(pl.z - tw), d3 = fabsf(pl.w - th);
                float sl = (d0 < 1.f ? 0.5f * d0 * d0 : d0 - 0.5f)
                         + (d1 < 1.f ? 0.5f * d1 * d1 : d1 - 0.5f)
                         + (d2 < 1.f ? 0.5f * d2 * d2 : d2 - 0.5f)
                         + (d3 < 1.f ? 0.5f * d3 * d3 : d3 - 0.5f);
                atomicAdd(&s_posce, ce);     // LDS atomics — per-CU, cheap
                atomicAdd(&s_sl1, sl);
                atomicAdd(&s_np, 1);
            }
            ceneg[idx] = cn;
        }
    }
    __syncthreads();
    if (tid == 0) {
        int slot = b * NBC + blockIdx.x;     // dedicated slot: zero global atomics
        pp_posce[slot] = s_posce;
        pp_sl1[slot]   = s_sl1;
        pp_np[slot]    = s_np;
    }
}

// ---------- kernel C: fold partials + exact top-K via bit-pattern binary search ----------
__global__ __launch_bounds__(512) void k_topk(
    const float* __restrict__ ceneg,
    const float* __restrict__ pp_posce, const float* __restrict__ pp_sl1,
    const int* __restrict__ pp_np,
    float* __restrict__ hard, float* __restrict__ posce_b,
    float* __restrict__ sl1_b, int* __restrict__ n_pos)
{
    int b = blockIdx.x, tid = threadIdx.x;
    __shared__ float4 sv4[PP / 4];           // 8732/4 = 2183
    __shared__ int s_i[8];
    __shared__ float s_f[8], s_f2[8];
    __shared__ int s_bcast;
    float pc = 0.f, sl = 0.f; int np = 0;
    for (int i = tid; i < NBC; i += 512) {
        pc += pp_posce[b * NBC + i];
        sl += pp_sl1[b * NBC + i];
        np += pp_np[b * NBC + i];
    }
    #pragma unroll
    for (int s = 32; s >= 1; s >>= 1) {
        pc += __shfl_xor(pc, s, 64);
        sl += __shfl_xor(sl, s, 64);
        np += __shfl_xor(np, s, 64);
    }
    int wid = tid >> 6;
    if ((tid & 63) == 0) { s_i[wid] = np; s_f[wid] = pc; s_f2[wid] = sl; }
    const float4* src = (const float4*)(ceneg + (size_t)b * PP);
    for (int i = tid; i < PP / 4; i += 512) sv4[i] = src[i];
    __syncthreads();
    if (tid == 0) {
        int n = 0; float fp = 0.f, fs = 0.f;
        #pragma unroll
        for (int k = 0; k < 8; ++k) { n += s_i[k]; fp += s_f[k]; fs += s_f2[k]; }
        n_pos[b] = n; posce_b[b] = fp; sl1_b[b] = fs;
        s_bcast = n;
    }
    __syncthreads();
    np = s_bcast;
    int K = 3 * (np > 1 ? np : 1);
    if (K > PP) K = PP;
    // invariant: cnt_ge(lo) >= K, cnt_ge(hi) < K; all values >= 0 so uint order == float order
    unsigned lo = 0u, hi = 0x7F800000u;
    while (hi - lo > 1u) {
        unsigned mid = (lo + hi) >> 1;
        float t = __uint_as_float(mid);
        int c = 0;
        for (int i = tid; i < PP / 4; i += 512) {
            float4 q = sv4[i];
            c += (q.x >= t) + (q.y >= t) + (q.z >= t) + (q.w >= t);
        }
        #pragma unroll
        for (int s = 32; s >= 1; s >>= 1) c += __shfl_xor(c, s, 64);
        if ((tid & 63) == 0) s_i[wid] = c;
        __syncthreads();
        if (tid == 0) {
            int n = 0;
            #pragma unroll
            for (int k = 0; k < 8; ++k) n += s_i[k];
            s_bcast = n;
        }
        __syncthreads();
        int cnt = s_bcast;
        if (cnt >= K) lo = mid; else hi = mid;
        __syncthreads();
    }
    float vk = __uint_as_float(lo);          // exact K-th largest value
    float sm = 0.f; int cg = 0;
    for (int i = tid; i < PP / 4; i += 512) {
        float4 q = sv4[i];
        if (q.x > vk) { sm += q.x; cg++; }
        if (q.y > vk) { sm += q.y; cg++; }
        if (q.z > vk) { sm += q.z; cg++; }
        if (q.w > vk) { sm += q.w; cg++; }
    }
    #pragma unroll
    for (int s = 32; s >= 1; s >>= 1) {
        sm += __shfl_xor(sm, s, 64);
        cg += __shfl_xor(cg, s, 64);
    }
    if ((tid & 63) == 0) { s_f[wid] = sm; s_i[wid] = cg; }
    __syncthreads();
    if (tid == 0) {
        float S = 0.f; int CG = 0;
        #pragma unroll
        for (int k = 0; k < 8; ++k) { S += s_f[k]; CG += s_i[k]; }
        hard[b] = S + (float)(K - CG) * vk;  // ties at vk handled exactly
    }
}

// ---------- kernel D: final combine ----------
__global__ void k_final(const int* __restrict__ n_pos, const float* __restrict__ hard,
                        const float* __restrict__ posce_b, const float* __restrict__ sl1_b,
                        float* __restrict__ out)
{
    int t = threadIdx.x;
    int np = (t < BB) ? n_pos[t] : 0;
    float h  = (t < BB) ? hard[t] : 0.f;
    float pc = (t < BB) ? posce_b[t] : 0.f;
    float sl = (t < BB) ? sl1_b[t] : 0.f;
    float cl = (t < BB) ? (float)(np > 1 ? np : 1) : 0.f;
    int tp = np; float hs = h; float cls = cl;
    #pragma unroll
    for (int s = 32; s >= 1; s >>= 1) {
        tp  += __shfl_xor(tp, s, 64);
        hs  += __shfl_xor(hs, s, 64);
        cls += __shfl_xor(cls, s, 64);
        pc  += __shfl_xor(pc, s, 64);
        sl  += __shfl_xor(sl, s, 64);
    }
    if (t == 0) {
        float conf = (hs + pc) / cls;
        float loc = 0.f;
        if (tp > 0) {
            int den = tp * 4; if (den < 1) den = 1;
            loc = sl / (float)den;
        }
        out[0] = conf + loc;
    }
}

extern "C" void kernel_launch(void* const* d_in, const int* in_sizes, int n_in,
                              void* d_out, int out_size, void* d_ws, size_t ws_size,
                              hipStream_t stream)
{
    const float* pred_locs   = (const float*)d_in[0];
    const float* pred_scores = (const float*)d_in[1];
    const float* gt_boxes    = (const float*)d_in[2];
    const int*   gt_labels   = (const int*)d_in[3];
    const float* priors      = (const float*)d_in[4];

    char* ws = (char*)d_ws;
    const size_t npf = (size_t)BB * PP;          // 558,848
    size_t off = 0;
    float* ovl   = (float*)(ws + off); off += 4 * npf;
    int*   obj   = (int*)  (ws + off); off += 4 * npf;
    float* ceneg = (float*)(ws + off); off += 4 * npf;   // 16B-aligned
    unsigned long long* part = (unsigned long long*)(ws + off); off += 8 * (size_t)BB * NBM * OO;
    float* pp_posce = (float*)(ws + off); off += 4 * (size_t)BB * NBC;
    float* pp_sl1   = (float*)(ws + off); off += 4 * (size_t)BB * NBC;
    int*   pp_np    = (int*)  (ws + off); off += 4 * (size_t)BB * NBC;
    float* posce_b  = (float*)(ws + off); off += 4 * BB;
    float* sl1_b    = (float*)(ws + off); off += 4 * BB;
    int*   n_pos    = (int*)  (ws + off); off += 4 * BB;
    float* hard     = (float*)(ws + off); off += 4 * BB;
    // no memsets needed: every scratch word is written before it is read

    dim3 gM(NBM, BB);
    k_match<<<gM, 256, 0, stream>>>(gt_boxes, (const float4*)priors, ovl, obj, part);

    k_force<<<BB, 64, 0, stream>>>(part, ovl, obj);

    dim3 gC(NBC, BB);
    k_ce<<<gC, 256, 0, stream>>>(pred_scores, (const float4*)pred_locs, gt_boxes,
                                 gt_labels, (const float4*)priors, ovl, obj,
                                 ceneg, pp_posce, pp_sl1, pp_np);

    k_topk<<<BB, 512, 0, stream>>>(ceneg, pp_posce, pp_sl1, pp_np,
                                   hard, posce_b, sl1_b, n_pos);

    k_final<<<1, 64, 0, stream>>>(n_pos, hard, posce_b, sl1_b, (float*)d_out);
}

// Round 6
// 320.789 us; speedup vs baseline: 1.0194x; 1.0194x over previous
//
#include <hip/hip_runtime.h>
#include <cstdint>
#include <cstddef>

#define BB 64
#define PP 8732
#define OO 32
#define CC 81
#define NBM 35    // k_match blocks per image (ceil(8732/256))
#define NBC 137   // k_ce blocks per image (64 priors each; 137*64=8768)

// ---------- helpers ----------
__device__ inline unsigned long long shfl_xor_u64(unsigned long long x, int m) {
    unsigned lo = (unsigned)x, hi = (unsigned)(x >> 32);
    lo = (unsigned)__shfl_xor((int)lo, m, 64);
    hi = (unsigned)__shfl_xor((int)hi, m, 64);
    return ((unsigned long long)hi << 32) | lo;
}

// ---------- kernel A: per-prior best object + per-block per-object best prior ----------
__global__ __launch_bounds__(256) void k_match(
    const float* __restrict__ gt_boxes,      // [B,O,4] coco pixel
    const float4* __restrict__ priors,       // [P] cxcy
    float* __restrict__ ovl, int* __restrict__ obj,
    unsigned long long* __restrict__ part)   // [B,NBM,O] packed (iou_bits<<32)|(~p)
{
    int b = blockIdx.y, blk = blockIdx.x;
    int tid = threadIdx.x;
    int p = blk * 256 + tid;
    bool pv = p < PP;
    __shared__ float bx1[OO], by1[OO], bx2[OO], by2[OO], bar[OO];
    __shared__ float mat[OO][264];           // stride 264 -> 2-way banks max (free)
    __shared__ unsigned long long po[OO][8];
    if (tid < OO) {
        const float* g = gt_boxes + ((size_t)b * OO + tid) * 4;
        float x1 = g[0] / 224.0f, y1 = g[1] / 224.0f;
        float x2 = (g[0] + g[2]) / 224.0f, y2 = (g[1] + g[3]) / 224.0f;
        bx1[tid] = x1; by1[tid] = y1; bx2[tid] = x2; by2[tid] = y2;
        bar[tid] = (x2 - x1) * (y2 - y1);
    }
    __syncthreads();
    float4 pr = priors[pv ? p : 0];
    float px1 = pr.x - pr.z * 0.5f, py1 = pr.y - pr.w * 0.5f;
    float px2 = pr.x + pr.z * 0.5f, py2 = pr.y + pr.w * 0.5f;
    float parea = (px2 - px1) * (py2 - py1);
    float best = -1.0f; int bo = 0;
    #pragma unroll
    for (int o = 0; o < OO; ++o) {
        float lx = fmaxf(bx1[o], px1), ly = fmaxf(by1[o], py1);
        float rx = fminf(bx2[o], px2), ry = fminf(by2[o], py2);
        float w = fmaxf(rx - lx, 0.0f), h = fmaxf(ry - ly, 0.0f);
        float inter = w * h;
        float iou = inter / (bar[o] + parea - inter);
        iou = pv ? iou : 0.0f;               // invalid priors can't win
        mat[o][tid] = iou;
        if (iou > best) { best = iou; bo = o; }   // strict > : first max (numpy argmax)
    }
    if (pv) {
        size_t idx = (size_t)b * PP + p;
        ovl[idx] = best;
        obj[idx] = bo;
    }
    __syncthreads();
    // per-object partial argmax over this block's 256 priors
    {
        int o = tid >> 3, j = tid & 7;
        float bv = -1.0f; int bt = 0;
        #pragma unroll
        for (int k = 0; k < 32; ++k) {
            int t = j + 8 * k;
            float v = mat[o][t];
            if (v > bv) { bv = v; bt = t; }
        }
        unsigned pg = (unsigned)(blk * 256 + bt);
        po[o][j] = ((unsigned long long)__float_as_uint(bv) << 32)
                 | (unsigned long long)(0xFFFFFFFFu - pg);
    }
    __syncthreads();
    if (tid < OO) {
        unsigned long long m = po[tid][0];
        #pragma unroll
        for (int j = 1; j < 8; ++j) if (po[tid][j] > m) m = po[tid][j];
        part[((size_t)b * NBM + blk) * OO + tid] = m;
    }
}

// ---------- kernel A2: fold partials + forced assignment (ascending o = numpy last-wins) ----------
__global__ void k_force(const unsigned long long* __restrict__ part,
                        float* __restrict__ ovl, int* __restrict__ obj)
{
    int b = blockIdx.x;
    __shared__ int s_pfo[OO];
    int t = threadIdx.x;
    if (t < OO) {
        unsigned long long m = part[((size_t)b * NBM + 0) * OO + t];
        for (int blk = 1; blk < NBM; ++blk) {
            unsigned long long v = part[((size_t)b * NBM + blk) * OO + t];
            if (v > m) m = v;                // packed max: larger iou, then smaller p
        }
        s_pfo[t] = (int)(0xFFFFFFFFu - (unsigned)(m & 0xFFFFFFFFull));
    }
    __syncthreads();
    if (t == 0) {
        for (int o = 0; o < OO; ++o) {
            int p = s_pfo[o];
            obj[(size_t)b * PP + p] = o;
            ovl[(size_t)b * PP + p] = 1.0f;
        }
    }
}

// ---------- kernel B: fused CE + loc loss, direct loads, 4 priors per 16-lane group ----------
__global__ __launch_bounds__(256) void k_ce(
    const float* __restrict__ scores,        // [B,P,C]
    const float4* __restrict__ pred_locs,
    const float* __restrict__ gt_boxes,
    const int* __restrict__ gt_labels,
    const float4* __restrict__ priors,
    const float* __restrict__ ovl, const int* __restrict__ obj,
    float* __restrict__ ceneg,
    float* __restrict__ pp_posce, float* __restrict__ pp_sl1,
    int* __restrict__ pp_np)
{
    int b = blockIdx.y;
    int group = threadIdx.x >> 4, lane = threadIdx.x & 15;
    int pbase = blockIdx.x * 64 + group;
    __shared__ float s_posce, s_sl1;
    __shared__ int s_np;
    if (threadIdx.x == 0) { s_posce = 0.f; s_sl1 = 0.f; s_np = 0; }
    __syncthreads();
    bool vv[4]; size_t ii[4]; int lab[4], ob[4];
    #pragma unroll
    for (int q = 0; q < 4; ++q) {
        int p = pbase + 16 * q;
        vv[q] = p < PP;
        ii[q] = (size_t)b * PP + (size_t)(vv[q] ? p : 0);
        lab[q] = 0; ob[q] = 0;
        if (vv[q]) {
            float ov = ovl[ii[q]];
            ob[q] = obj[ii[q]];
            lab[q] = (ov < 0.5f) ? 0 : gt_labels[b * OO + ob[q]];
        }
    }
    float a[4][6];
    #pragma unroll
    for (int q = 0; q < 4; ++q) {
        const float* r = scores + ii[q] * CC;
        #pragma unroll
        for (int k = 0; k < 6; ++k) {
            int c = lane + 16 * k;
            a[q][k] = (vv[q] && c < CC) ? r[c] : -INFINITY;
        }
    }
    float se[4] = {0.f, 0.f, 0.f, 0.f}, xl[4] = {0.f, 0.f, 0.f, 0.f};
    #pragma unroll
    for (int k = 0; k < 6; ++k) {
        int c = lane + 16 * k;
        if (c < CC) {
            #pragma unroll
            for (int q = 0; q < 4; ++q) {
                se[q] += __expf(a[q][k]);
                if (c == lab[q]) xl[q] = a[q][k];
            }
        }
    }
    #pragma unroll
    for (int s = 8; s >= 1; s >>= 1) {
        #pragma unroll
        for (int q = 0; q < 4; ++q) {
            se[q] += __shfl_xor(se[q], s, 16);
            xl[q] += __shfl_xor(xl[q], s, 16);
        }
    }
    if (lane == 0) {
        #pragma unroll
        for (int q = 0; q < 4; ++q) {
            if (!vv[q]) continue;
            size_t idx = ii[q];
            int p = pbase + 16 * q;
            float ce = fmaxf(__logf(se[q]) - xl[q], 0.0f);
            float cn = ce;
            if (lab[q] != 0) {
                cn = 0.f;
                int o = ob[q];
                float4 pl = pred_locs[idx];
                float4 pq = priors[p];
                const float* g = gt_boxes + ((size_t)b * OO + o) * 4;
                float x1 = g[0] / 224.0f, y1 = g[1] / 224.0f;
                float x2 = (g[0] + g[2]) / 224.0f, y2 = (g[1] + g[3]) / 224.0f;
                float cx = (x1 + x2) * 0.5f, cy = (y1 + y2) * 0.5f;
                float w = x2 - x1, h = y2 - y1;
                float tx = (cx - pq.x) / (pq.z / 10.0f);
                float ty = (cy - pq.y) / (pq.w / 10.0f);
                float tw = __logf(w / pq.z) * 5.0f;
                float th = __logf(h / pq.w) * 5.0f;
                float d0 = fabsf(pl.x - tx), d1 = fabsf(pl.y - ty);
                float d2 = fabsf(pl.z - tw), d3 = fabsf(pl.w - th);
                float sl = (d0 < 1.f ? 0.5f * d0 * d0 : d0 - 0.5f)
                         + (d1 < 1.f ? 0.5f * d1 * d1 : d1 - 0.5f)
                         + (d2 < 1.f ? 0.5f * d2 * d2 : d2 - 0.5f)
                         + (d3 < 1.f ? 0.5f * d3 * d3 : d3 - 0.5f);
                atomicAdd(&s_posce, ce);     // LDS atomics — per-CU, cheap
                atomicAdd(&s_sl1, sl);
                atomicAdd(&s_np, 1);
            }
            ceneg[idx] = cn;
        }
    }
    __syncthreads();
    if (threadIdx.x == 0) {
        int slot = b * NBC + blockIdx.x;     // dedicated slot: zero global atomics
        pp_posce[slot] = s_posce;
        pp_sl1[slot]   = s_sl1;
        pp_np[slot]    = s_np;
    }
}

// ---------- kernel C: fold partials + exact top-K via 3-bit multi-probe bisection ----------
__global__ __launch_bounds__(512) void k_topk(
    const float* __restrict__ ceneg,
    const float* __restrict__ pp_posce, const float* __restrict__ pp_sl1,
    const int* __restrict__ pp_np,
    float* __restrict__ hard, float* __restrict__ posce_b,
    float* __restrict__ sl1_b, int* __restrict__ n_pos)
{
    int b = blockIdx.x, tid = threadIdx.x;
    int wave = tid >> 6;
    __shared__ float4 sv4[PP / 4];           // 8732/4 = 2183
    __shared__ int s_i[8];
    __shared__ float s_f[8], s_f2[8];
    __shared__ int s_cnt[8][8];              // [wave][probe]
    __shared__ int s_tot[8];
    __shared__ int s_bcast;
    // fold per-block partials for this image
    float pc = 0.f, sl = 0.f; int np = 0;
    for (int i = tid; i < NBC; i += 512) {
        pc += pp_posce[b * NBC + i];
        sl += pp_sl1[b * NBC + i];
        np += pp_np[b * NBC + i];
    }
    #pragma unroll
    for (int s = 32; s >= 1; s >>= 1) {
        pc += __shfl_xor(pc, s, 64);
        sl += __shfl_xor(sl, s, 64);
        np += __shfl_xor(np, s, 64);
    }
    if ((tid & 63) == 0) { s_i[wave] = np; s_f[wave] = pc; s_f2[wave] = sl; }
    // stage ce_neg into LDS (float4)
    const float4* src = (const float4*)(ceneg + (size_t)b * PP);
    for (int i = tid; i < PP / 4; i += 512) sv4[i] = src[i];
    __syncthreads();
    if (tid == 0) {
        int n = 0; float fp = 0.f, fs = 0.f;
        #pragma unroll
        for (int k = 0; k < 8; ++k) { n += s_i[k]; fp += s_f[k]; fs += s_f2[k]; }
        n_pos[b] = n; posce_b[b] = fp; sl1_b[b] = fs;
        s_bcast = n;
    }
    __syncthreads();
    np = s_bcast;
    int K = 3 * (np > 1 ? np : 1);
    if (K > PP) K = PP;
    // invariant: cnt_ge(lo) >= K > cnt_ge(hi); values >= 0 so uint order == float order.
    // each round probes 7 interior thresholds -> interval shrinks ~8x -> ~11 rounds.
    unsigned lo = 0u, hi = 0x7F800000u;
    while (hi - lo > 1u) {
        unsigned range = hi - lo;
        unsigned step = range >> 3; if (step == 0u) step = 1u;
        unsigned tw[7]; float t[7];
        #pragma unroll
        for (int k = 0; k < 7; ++k) {
            unsigned u = lo + step * (unsigned)(k + 1);
            if (u > hi) u = hi;              // clamped probes give cnt < K, never selected
            tw[k] = u; t[k] = __uint_as_float(u);
        }
        int c[7] = {0, 0, 0, 0, 0, 0, 0};
        for (int i = tid; i < PP / 4; i += 512) {
            float4 q = sv4[i];
            #pragma unroll
            for (int k = 0; k < 7; ++k)
                c[k] += (q.x >= t[k]) + (q.y >= t[k]) + (q.z >= t[k]) + (q.w >= t[k]);
        }
        #pragma unroll
        for (int k = 0; k < 7; ++k)
            #pragma unroll
            for (int s = 32; s >= 1; s >>= 1) c[k] += __shfl_xor(c[k], s, 64);
        if ((tid & 63) == 0) {
            #pragma unroll
            for (int k = 0; k < 7; ++k) s_cnt[wave][k] = c[k];
        }
        __syncthreads();
        if (tid < 7) {
            int n = 0;
            #pragma unroll
            for (int w = 0; w < 8; ++w) n += s_cnt[w][tid];
            s_tot[tid] = n;
        }
        __syncthreads();
        int j = -1;
        #pragma unroll
        for (int k = 0; k < 7; ++k) if (s_tot[k] >= K) j = k;   // counts are monotone dec.
        lo = (j >= 0) ? tw[j] : lo;
        unsigned nhi = (j < 6) ? tw[j + 1] : hi;
        hi = (nhi < hi) ? nhi : hi;
    }
    float vk = __uint_as_float(lo);          // exact K-th largest value
    float sm = 0.f; int cg = 0;
    for (int i = tid; i < PP / 4; i += 512) {
        float4 q = sv4[i];
        if (q.x > vk) { sm += q.x; cg++; }
        if (q.y > vk) { sm += q.y; cg++; }
        if (q.z > vk) { sm += q.z; cg++; }
        if (q.w > vk) { sm += q.w; cg++; }
    }
    #pragma unroll
    for (int s = 32; s >= 1; s >>= 1) {
        sm += __shfl_xor(sm, s, 64);
        cg += __shfl_xor(cg, s, 64);
    }
    if ((tid & 63) == 0) { s_f[wave] = sm; s_i[wave] = cg; }
    __syncthreads();
    if (tid == 0) {
        float S = 0.f; int CG = 0;
        #pragma unroll
        for (int k = 0; k < 8; ++k) { S += s_f[k]; CG += s_i[k]; }
        hard[b] = S + (float)(K - CG) * vk;  // ties at vk handled exactly
    }
}

// ---------- kernel D: final combine ----------
__global__ void k_final(const int* __restrict__ n_pos, const float* __restrict__ hard,
                        const float* __restrict__ posce_b, const float* __restrict__ sl1_b,
                        float* __restrict__ out)
{
    int t = threadIdx.x;
    int np = (t < BB) ? n_pos[t] : 0;
    float h  = (t < BB) ? hard[t] : 0.f;
    float pc = (t < BB) ? posce_b[t] : 0.f;
    float sl = (t < BB) ? sl1_b[t] : 0.f;
    float cl = (t < BB) ? (float)(np > 1 ? np : 1) : 0.f;
    int tp = np; float hs = h; float cls = cl;
    #pragma unroll
    for (int s = 32; s >= 1; s >>= 1) {
        tp  += __shfl_xor(tp, s, 64);
        hs  += __shfl_xor(hs, s, 64);
        cls += __shfl_xor(cls, s, 64);
        pc  += __shfl_xor(pc, s, 64);
        sl  += __shfl_xor(sl, s, 64);
    }
    if (t == 0) {
        float conf = (hs + pc) / cls;
        float loc = 0.f;
        if (tp > 0) {
            int den = tp * 4; if (den < 1) den = 1;
            loc = sl / (float)den;
        }
        out[0] = conf + loc;
    }
}

extern "C" void kernel_launch(void* const* d_in, const int* in_sizes, int n_in,
                              void* d_out, int out_size, void* d_ws, size_t ws_size,
                              hipStream_t stream)
{
    const float* pred_locs   = (const float*)d_in[0];
    const float* pred_scores = (const float*)d_in[1];
    const float* gt_boxes    = (const float*)d_in[2];
    const int*   gt_labels   = (const int*)d_in[3];
    const float* priors      = (const float*)d_in[4];

    char* ws = (char*)d_ws;
    const size_t npf = (size_t)BB * PP;          // 558,848
    size_t off = 0;
    float* ovl   = (float*)(ws + off); off += 4 * npf;
    int*   obj   = (int*)  (ws + off); off += 4 * npf;
    float* ceneg = (float*)(ws + off); off += 4 * npf;   // 16B-aligned
    unsigned long long* part = (unsigned long long*)(ws + off); off += 8 * (size_t)BB * NBM * OO;
    float* pp_posce = (float*)(ws + off); off += 4 * (size_t)BB * NBC;
    float* pp_sl1   = (float*)(ws + off); off += 4 * (size_t)BB * NBC;
    int*   pp_np    = (int*)  (ws + off); off += 4 * (size_t)BB * NBC;
    float* posce_b  = (float*)(ws + off); off += 4 * BB;
    float* sl1_b    = (float*)(ws + off); off += 4 * BB;
    int*   n_pos    = (int*)  (ws + off); off += 4 * BB;
    float* hard     = (float*)(ws + off); off += 4 * BB;
    // no memsets needed: every scratch word is written before it is read

    dim3 gM(NBM, BB);
    k_match<<<gM, 256, 0, stream>>>(gt_boxes, (const float4*)priors, ovl, obj, part);

    k_force<<<BB, 64, 0, stream>>>(part, ovl, obj);

    dim3 gC(NBC, BB);
    k_ce<<<gC, 256, 0, stream>>>(pred_scores, (const float4*)pred_locs, gt_boxes,
                                 gt_labels, (const float4*)priors, ovl, obj,
                                 ceneg, pp_posce, pp_sl1, pp_np);

    k_topk<<<BB, 512, 0, stream>>>(ceneg, pp_posce, pp_sl1, pp_np,
                                   hard, posce_b, sl1_b, n_pos);

    k_final<<<1, 64, 0, stream>>>(n_pos, hard, posce_b, sl1_b, (float*)d_out);
}